// Round 1
// baseline (820.851 us; speedup 1.0000x reference)
//
#include <hip/hip_runtime.h>

#define S_LEN 2048
#define D_DIM 64
#define BH_N  32
#define QT    128
#define KT    128
#define NTHR  256
#define PROB_ELEMS 4194304LL  // 2*16*2048*64

// -------------------------------------------------------------------------
// Probe: decide whether the bool mask was uploaded as int32 (flag=1) or as
// 1-byte elements (flag=0). int32 upload => first 64 words are all 0/1.
// Byte upload => words are packed 0/1 bytes, virtually never all <= 1.
// Deterministic: depends only on input contents.
// -------------------------------------------------------------------------
__global__ void mask_probe_kernel(const unsigned int* __restrict__ m,
                                  int* __restrict__ flag) {
    unsigned int v = m[threadIdx.x];
    unsigned long long ok = __ballot(v <= 1u);
    if (threadIdx.x == 0) *flag = (ok == ~0ULL) ? 1 : 0;
}

// -------------------------------------------------------------------------
// K1: per (bh, q-tile of 128): for each k-tile of 128 compute
// e = exp(mask ? -inf : Q.K/8), write unnormalized e into the attn output
// region, accumulate per-row sums into ws. Max-free softmax (|score|<=~8).
// 256 threads, 8x8 scores per thread. LDS XOR-swizzled (slot = d4 ^ (row>>2)&15)
// to avoid the 8-way bank conflict of stride-64 fp32 rows on ds_read_b128.
// -------------------------------------------------------------------------
__global__ __launch_bounds__(NTHR)
void qk_exp_kernel(const float* __restrict__ Qg, const float* __restrict__ Kg,
                   const unsigned char* __restrict__ maskB,
                   const int* __restrict__ flagp,
                   float* __restrict__ attn, float* __restrict__ rowsum) {
    __shared__ float Qs[QT * 64];   // swizzled: (r,d) -> [r*64 + ((d>>2 ^ (r>>2)&15)<<2) + (d&3)]
    __shared__ float Ks[KT * 64];

    const int t  = threadIdx.x;
    const int qt = blockIdx.x;
    const int bh = blockIdx.y;
    const int tq = t >> 4;    // 0..15 -> rows {4tq+i, 64+4tq+i}
    const int tk = t & 15;    // 0..15 -> cols {4tk+j, 64+4tk+j}
    const int mask32 = *flagp;

    const long long qrowg = (long long)bh * S_LEN + (long long)qt * QT;

    // stage Q tile (128 x 64), swizzled
    #pragma unroll
    for (int i8 = 0; i8 < 8; ++i8) {
        int flat = t + NTHR * i8;           // 0..2047
        int r = flat >> 4, d4 = flat & 15;
        float4 v = *(const float4*)&Qg[(qrowg + r) * D_DIM + (d4 << 2)];
        int slot = d4 ^ ((r >> 2) & 15);
        *(float4*)&Qs[(r << 6) + (slot << 2)] = v;
    }

    float psum[8];
    #pragma unroll
    for (int z = 0; z < 8; ++z) psum[z] = 0.0f;

    const long long krowg = (long long)bh * S_LEN;

    for (int kt = 0; kt < S_LEN / KT; ++kt) {
        __syncthreads();   // protect Ks reuse (and Qs on first iter)
        #pragma unroll
        for (int i8 = 0; i8 < 8; ++i8) {
            int flat = t + NTHR * i8;
            int r = flat >> 4, d4 = flat & 15;
            float4 v = *(const float4*)&Kg[(krowg + (long long)kt * KT + r) * D_DIM + (d4 << 2)];
            int slot = d4 ^ ((r >> 2) & 15);
            *(float4*)&Ks[(r << 6) + (slot << 2)] = v;
        }
        __syncthreads();

        float s[8][8];
        #pragma unroll
        for (int a = 0; a < 8; ++a)
            #pragma unroll
            for (int b = 0; b < 8; ++b) s[a][b] = 0.0f;

        #pragma unroll 4
        for (int d4 = 0; d4 < 16; ++d4) {
            float4 qf[8], kf[8];
            const int sq = (d4 ^ tq) << 2;
            const int sk = (d4 ^ tk) << 2;
            #pragma unroll
            for (int a = 0; a < 8; ++a) {
                int r = ((a >> 2) << 6) + (tq << 2) + (a & 3);
                qf[a] = *(const float4*)&Qs[(r << 6) + sq];
            }
            #pragma unroll
            for (int b = 0; b < 8; ++b) {
                int c = ((b >> 2) << 6) + (tk << 2) + (b & 3);
                kf[b] = *(const float4*)&Ks[(c << 6) + sk];
            }
            #pragma unroll
            for (int a = 0; a < 8; ++a) {
                #pragma unroll
                for (int b = 0; b < 8; ++b) {
                    s[a][b] = fmaf(qf[a].x, kf[b].x, s[a][b]);
                    s[a][b] = fmaf(qf[a].y, kf[b].y, s[a][b]);
                    s[a][b] = fmaf(qf[a].z, kf[b].z, s[a][b]);
                    s[a][b] = fmaf(qf[a].w, kf[b].w, s[a][b]);
                }
            }
        }

        // mask + exp + write unnormalized e + row partial sums
        #pragma unroll
        for (int a = 0; a < 8; ++a) {
            const int r = ((a >> 2) << 6) + (tq << 2) + (a & 3);
            const long long rowg = (long long)bh * S_LEN + qt * QT + r;
            const long long base = rowg * S_LEN + (long long)kt * KT;
            #pragma unroll
            for (int jh = 0; jh < 2; ++jh) {
                const int col = (jh << 6) + (tk << 2);
                int mk0, mk1, mk2, mk3;
                if (mask32) {
                    const int4 m = *(const int4*)(((const int*)maskB) + (base + col));
                    mk0 = m.x; mk1 = m.y; mk2 = m.z; mk3 = m.w;
                } else {
                    const unsigned int mb = *(const unsigned int*)(maskB + (base + col));
                    mk0 = mb & 0xff; mk1 = (mb >> 8) & 0xff;
                    mk2 = (mb >> 16) & 0xff; mk3 = mb >> 24;
                }
                float4 ev;
                ev.x = mk0 ? 0.0f : __expf(s[a][(jh << 2) + 0] * 0.125f);
                ev.y = mk1 ? 0.0f : __expf(s[a][(jh << 2) + 1] * 0.125f);
                ev.z = mk2 ? 0.0f : __expf(s[a][(jh << 2) + 2] * 0.125f);
                ev.w = mk3 ? 0.0f : __expf(s[a][(jh << 2) + 3] * 0.125f);
                psum[a] += ev.x + ev.y + ev.z + ev.w;
                *(float4*)&attn[base + col] = ev;
            }
        }
    }

    // reduce row sums across the 16 tk-lanes (contiguous 16-lane groups)
    #pragma unroll
    for (int off = 1; off < 16; off <<= 1) {
        #pragma unroll
        for (int z = 0; z < 8; ++z) psum[z] += __shfl_xor(psum[z], off, 64);
    }
    if (tk == 0) {
        #pragma unroll
        for (int z = 0; z < 8; ++z) {
            int r = ((z >> 2) << 6) + (tq << 2) + (z & 3);
            rowsum[bh * S_LEN + qt * QT + r] = psum[z];
        }
    }
}

// -------------------------------------------------------------------------
// K3: per (bh, q-tile of 128): read back unnormalized e tiles, rescale by
// 1/rowsum (write final attn in place), and accumulate prob = attn . V.
// A-tiles transposed into LDS so the PV inner loop is all ds_read_b128.
// -------------------------------------------------------------------------
__global__ __launch_bounds__(NTHR)
void pv_norm_kernel(const float* __restrict__ Vg, float* __restrict__ attn,
                    const float* __restrict__ rowsum, float* __restrict__ prob) {
    __shared__ float AeT[64 * 132];  // [k][q], padded stride 132
    __shared__ float Vs[64 * 68];    // [k][d], padded stride 68
    __shared__ float rinv[QT];

    const int t   = threadIdx.x;
    const int qt  = blockIdx.x;
    const int bh  = blockIdx.y;
    const int tqp = t >> 4;   // q0 = 8*tqp
    const int td  = t & 15;   // d0 = 4*td

    if (t < QT) rinv[t] = 1.0f / rowsum[bh * S_LEN + qt * QT + t];

    float4 pv[8];
    #pragma unroll
    for (int a = 0; a < 8; ++a) pv[a] = make_float4(0.f, 0.f, 0.f, 0.f);

    const long long vrowg = (long long)bh * S_LEN;

    for (int kc = 0; kc < S_LEN / 64; ++kc) {
        __syncthreads();  // covers rinv on iter 0 and AeT/Vs reuse after

        // stage A tile (128 q x 64 k): read e, rescale, write back attn,
        // scatter transposed into LDS
        #pragma unroll
        for (int i8 = 0; i8 < 8; ++i8) {
            int flat = t + NTHR * i8;          // 0..2047
            int r = flat >> 4, c4 = flat & 15;
            long long gidx = ((long long)bh * S_LEN + qt * QT + r) * S_LEN
                             + (long long)kc * 64 + (c4 << 2);
            float4 g = *(const float4*)&attn[gidx];
            float w = rinv[r];
            g.x *= w; g.y *= w; g.z *= w; g.w *= w;
            *(float4*)&attn[gidx] = g;
            int cb = c4 << 2;
            AeT[(cb + 0) * 132 + r] = g.x;
            AeT[(cb + 1) * 132 + r] = g.y;
            AeT[(cb + 2) * 132 + r] = g.z;
            AeT[(cb + 3) * 132 + r] = g.w;
        }
        // stage V tile (64 k x 64 d)
        #pragma unroll
        for (int i4 = 0; i4 < 4; ++i4) {
            int flat = t + NTHR * i4;          // 0..1023
            int r = flat >> 4, d4 = flat & 15;
            *(float4*)&Vs[r * 68 + (d4 << 2)] =
                *(const float4*)&Vg[(vrowg + (long long)kc * 64 + r) * D_DIM + (d4 << 2)];
        }
        __syncthreads();

        #pragma unroll 8
        for (int k = 0; k < 64; ++k) {
            float4 v4 = *(const float4*)&Vs[k * 68 + (td << 2)];
            float4 a0 = *(const float4*)&AeT[k * 132 + (tqp << 3)];
            float4 a1 = *(const float4*)&AeT[k * 132 + (tqp << 3) + 4];
#define PV_FMA(idx, av)                              \
            pv[idx].x = fmaf(av, v4.x, pv[idx].x);   \
            pv[idx].y = fmaf(av, v4.y, pv[idx].y);   \
            pv[idx].z = fmaf(av, v4.z, pv[idx].z);   \
            pv[idx].w = fmaf(av, v4.w, pv[idx].w);
            PV_FMA(0, a0.x) PV_FMA(1, a0.y) PV_FMA(2, a0.z) PV_FMA(3, a0.w)
            PV_FMA(4, a1.x) PV_FMA(5, a1.y) PV_FMA(6, a1.z) PV_FMA(7, a1.w)
#undef PV_FMA
        }
    }

    #pragma unroll
    for (int a = 0; a < 8; ++a) {
        long long gq = (long long)bh * S_LEN + qt * QT + (tqp << 3) + a;
        *(float4*)&prob[gq * D_DIM + (td << 2)] = pv[a];
    }
}

// -------------------------------------------------------------------------
extern "C" void kernel_launch(void* const* d_in, const int* in_sizes, int n_in,
                              void* d_out, int out_size, void* d_ws, size_t ws_size,
                              hipStream_t stream) {
    const float* Q = (const float*)d_in[0];
    const float* K = (const float*)d_in[1];
    const float* V = (const float*)d_in[2];
    const unsigned char* mask = (const unsigned char*)d_in[3];

    float* prob = (float*)d_out;
    float* attn = (float*)d_out + PROB_ELEMS;

    int*   flag   = (int*)d_ws;
    float* rowsum = (float*)d_ws + 64;   // 65536 floats

    mask_probe_kernel<<<1, 64, 0, stream>>>((const unsigned int*)mask, flag);
    qk_exp_kernel<<<dim3(S_LEN / QT, BH_N), NTHR, 0, stream>>>(Q, K, mask, flag, attn, rowsum);
    pv_norm_kernel<<<dim3(S_LEN / QT, BH_N), NTHR, 0, stream>>>(V, attn, rowsum, prob);
}

// Round 2
// 544.463 us; speedup vs baseline: 1.5076x; 1.5076x over previous
//
#include <hip/hip_runtime.h>
#include <hip/hip_bf16.h>

#define S_LEN 2048
#define D_DIM 64
#define QT    128
#define KT    128
#define NTHR  256
#define NKT   (S_LEN / KT)          // 16
#define NBLK  512                   // 16 q-tiles * 32 bh
#define PROB_ELEMS 4194304LL        // 2*16*2048*64

typedef float f32x4  __attribute__((ext_vector_type(4)));
typedef short bf16x8 __attribute__((ext_vector_type(8)));

__device__ __forceinline__ unsigned short f2bf(float f) {
    return __builtin_bit_cast(unsigned short, __float2bfloat16(f));
}

// -------------------------------------------------------------------------
// Probe: mask uploaded as int32 (flag=1) or bytes (flag=0). R1 FETCH_SIZE
// evidence says int32; keep the hedge (costs ~2us).
// -------------------------------------------------------------------------
__global__ void mask_probe_kernel(const unsigned int* __restrict__ m,
                                  int* __restrict__ flag) {
    unsigned int v = m[threadIdx.x];
    unsigned long long ok = __ballot(v <= 1u);
    if (threadIdx.x == 0) *flag = (ok == ~0ULL) ? 1 : 0;
}

// Common per-thread geometry:
//  t in [0,256), lane = t&63, wave w = t>>6 owns q-rows [32w,32w+32)
//  c = lane&15 (MFMA col), g = lane>>4 (MFMA row group)
//  QK MFMA 16x16x32: A(Q): row=lane&15, k=8*(lane>>4)+j ; B(K^T): same gather
//  C/D: col=lane&15, row=4*(lane>>4)+reg   [guide §3, m89-verified]

// -------------------------------------------------------------------------
// Sweep 1: rowsums (+ packed mask bits into ws). No attn writes.
// -------------------------------------------------------------------------
__global__ __launch_bounds__(NTHR, 2)
void attn_sweep1(const float* __restrict__ Qg, const float* __restrict__ Kg,
                 const unsigned char* __restrict__ maskB,
                 const int* __restrict__ flagp,
                 float* __restrict__ rinvWS,
                 unsigned long long* __restrict__ bitsWS, int useWS) {
    __shared__ unsigned char sm[32768];     // Qs [0,16K), Ks [16K,32K)
    unsigned char* Qs = sm;
    unsigned char* Ks = sm + 16384;

    const int t = threadIdx.x;
    const int lane = t & 63, w = t >> 6, c = lane & 15, g = lane >> 4;

    const int orig = blockIdx.x;
    const int virt = (orig & 7) * 64 + (orig >> 3);   // XCD swizzle: 4 bh/XCD
    const int qt = virt & 15, bh = virt >> 4;
    const int mask32 = *flagp;

    const int qrowbase = bh * S_LEN + qt * QT;
    const int kbase0 = bh * S_LEN;

    // ---- stage Q (fp32 -> bf16, 16B-chunk XOR swizzle) ----
    #pragma unroll
    for (int i = 0; i < 4; ++i) {
        int flat = i * NTHR + t, row = flat >> 3, ch = flat & 7;
        const float* src = Qg + (qrowbase + row) * D_DIM + ch * 8;
        float4 a = *(const float4*)src, b = *(const float4*)(src + 4);
        bf16x8 hv;
        hv[0]=(short)f2bf(a.x); hv[1]=(short)f2bf(a.y); hv[2]=(short)f2bf(a.z); hv[3]=(short)f2bf(a.w);
        hv[4]=(short)f2bf(b.x); hv[5]=(short)f2bf(b.y); hv[6]=(short)f2bf(b.z); hv[7]=(short)f2bf(b.w);
        *(bf16x8*)(Qs + row * 128 + ((ch ^ (row & 7)) << 4)) = hv;
    }
    __syncthreads();
    bf16x8 qf[2][2];
    #pragma unroll
    for (int m = 0; m < 2; ++m)
        #pragma unroll
        for (int kk = 0; kk < 2; ++kk) {
            int row = w * 32 + m * 16 + c, ch = kk * 4 + g;
            qf[m][kk] = *(const bf16x8*)(Qs + row * 128 + ((ch ^ (row & 7)) << 4));
        }

    unsigned rowoff[2][4];
    #pragma unroll
    for (int m = 0; m < 2; ++m)
        #pragma unroll
        for (int r = 0; r < 4; ++r)
            rowoff[m][r] = (unsigned)(qrowbase + w * 32 + m * 16 + g * 4 + r) * (unsigned)S_LEN;

    float psum[2][4] = {{0.f,0.f,0.f,0.f},{0.f,0.f,0.f,0.f}};

    // prefetch K tile 0 into registers (T14 async-stage)
    float kpre[32];
    #pragma unroll
    for (int i = 0; i < 4; ++i) {
        int flat = i * NTHR + t, row = flat >> 3, ch = flat & 7;
        const float* src = Kg + (kbase0 + row) * D_DIM + ch * 8;
        float4 a = *(const float4*)src, b = *(const float4*)(src + 4);
        kpre[i*8+0]=a.x; kpre[i*8+1]=a.y; kpre[i*8+2]=a.z; kpre[i*8+3]=a.w;
        kpre[i*8+4]=b.x; kpre[i*8+5]=b.y; kpre[i*8+6]=b.z; kpre[i*8+7]=b.w;
    }

    for (int kt = 0; kt < NKT; ++kt) {
        __syncthreads();                        // prev Ks reads done
        #pragma unroll
        for (int i = 0; i < 4; ++i) {
            int flat = i * NTHR + t, row = flat >> 3, ch = flat & 7;
            bf16x8 hv;
            #pragma unroll
            for (int j = 0; j < 8; ++j) hv[j] = (short)f2bf(kpre[i*8+j]);
            *(bf16x8*)(Ks + row * 128 + ((ch ^ (row & 7)) << 4)) = hv;
        }
        if (kt + 1 < NKT) {
            #pragma unroll
            for (int i = 0; i < 4; ++i) {
                int flat = i * NTHR + t, row = flat >> 3, ch = flat & 7;
                const float* src = Kg + (kbase0 + (kt+1)*KT + row) * D_DIM + ch * 8;
                float4 a = *(const float4*)src, b = *(const float4*)(src + 4);
                kpre[i*8+0]=a.x; kpre[i*8+1]=a.y; kpre[i*8+2]=a.z; kpre[i*8+3]=a.w;
                kpre[i*8+4]=b.x; kpre[i*8+5]=b.y; kpre[i*8+6]=b.z; kpre[i*8+7]=b.w;
            }
        }
        __syncthreads();                        // Ks ready

        unsigned long long bits = 0ull;
        const unsigned kcb = (unsigned)(kt * KT + c);
        #pragma unroll
        for (int n = 0; n < 8; ++n) {
            int rowk = n * 16 + c;
            bf16x8 b0 = *(const bf16x8*)(Ks + rowk * 128 + (((0 + g) ^ (rowk & 7)) << 4));
            bf16x8 b1 = *(const bf16x8*)(Ks + rowk * 128 + (((4 + g) ^ (rowk & 7)) << 4));
            f32x4 a0 = {0.f,0.f,0.f,0.f}, a1 = {0.f,0.f,0.f,0.f};
            a0 = __builtin_amdgcn_mfma_f32_16x16x32_bf16(qf[0][0], b0, a0, 0, 0, 0);
            a0 = __builtin_amdgcn_mfma_f32_16x16x32_bf16(qf[0][1], b1, a0, 0, 0, 0);
            a1 = __builtin_amdgcn_mfma_f32_16x16x32_bf16(qf[1][0], b0, a1, 0, 0, 0);
            a1 = __builtin_amdgcn_mfma_f32_16x16x32_bf16(qf[1][1], b1, a1, 0, 0, 0);
            #pragma unroll
            for (int m = 0; m < 2; ++m) {
                f32x4 am = m ? a1 : a0;
                #pragma unroll
                for (int r = 0; r < 4; ++r) {
                    unsigned idx = rowoff[m][r] + kcb + n * 16;
                    int mk;
                    if (mask32) mk = __builtin_nontemporal_load(((const int*)maskB) + idx);
                    else        mk = (int)__builtin_nontemporal_load(maskB + idx);
                    float e = mk ? 0.f : __expf(am[r] * 0.125f);
                    psum[m][r] += e;
                    bits |= (unsigned long long)(mk ? 1u : 0u) << ((m << 5) | (n << 2) | r);
                }
            }
        }
        if (useWS) bitsWS[((unsigned)virt * NKT + kt) * NTHR + t] = bits;
    }

    #pragma unroll
    for (int m = 0; m < 2; ++m)
        #pragma unroll
        for (int r = 0; r < 4; ++r) {
            float s = psum[m][r];
            s += __shfl_xor(s, 1, 64);
            s += __shfl_xor(s, 2, 64);
            s += __shfl_xor(s, 4, 64);
            s += __shfl_xor(s, 8, 64);
            if (c == 0) rinvWS[virt * QT + w * 32 + m * 16 + g * 4 + r] = 1.0f / s;
        }
}

// -------------------------------------------------------------------------
// Sweep 2: recompute QK (MFMA), write normalized attn, fused PV (MFMA).
// LDS: P 32K [0,32K) (Q staging aliases) | Ks 16K | Vt 16K (transposed V).
// -------------------------------------------------------------------------
__global__ __launch_bounds__(NTHR, 2)
void attn_sweep2(const float* __restrict__ Qg, const float* __restrict__ Kg,
                 const float* __restrict__ Vg,
                 const unsigned char* __restrict__ maskB,
                 const int* __restrict__ flagp,
                 const float* __restrict__ rinvWS,
                 const unsigned long long* __restrict__ bitsWS, int useWS,
                 float* __restrict__ attnOut, float* __restrict__ probOut) {
    __shared__ unsigned char sm[65536];
    unsigned char* Ps = sm;               // 32 KB (also Q staging at start)
    unsigned char* Ks = sm + 32768;       // 16 KB
    unsigned char* Vt = sm + 49152;       // 16 KB, [d][k] bf16 transposed

    const int t = threadIdx.x;
    const int lane = t & 63, w = t >> 6, c = lane & 15, g = lane >> 4;

    const int orig = blockIdx.x;
    const int virt = (orig & 7) * 64 + (orig >> 3);
    const int qt = virt & 15, bh = virt >> 4;
    const int mask32 = *flagp;

    const int qrowbase = bh * S_LEN + qt * QT;
    const int kbase0 = bh * S_LEN;

    // ---- stage Q into Ps region, load A-frags ----
    #pragma unroll
    for (int i = 0; i < 4; ++i) {
        int flat = i * NTHR + t, row = flat >> 3, ch = flat & 7;
        const float* src = Qg + (qrowbase + row) * D_DIM + ch * 8;
        float4 a = *(const float4*)src, b = *(const float4*)(src + 4);
        bf16x8 hv;
        hv[0]=(short)f2bf(a.x); hv[1]=(short)f2bf(a.y); hv[2]=(short)f2bf(a.z); hv[3]=(short)f2bf(a.w);
        hv[4]=(short)f2bf(b.x); hv[5]=(short)f2bf(b.y); hv[6]=(short)f2bf(b.z); hv[7]=(short)f2bf(b.w);
        *(bf16x8*)(Ps + row * 128 + ((ch ^ (row & 7)) << 4)) = hv;
    }
    __syncthreads();
    bf16x8 qf[2][2];
    #pragma unroll
    for (int m = 0; m < 2; ++m)
        #pragma unroll
        for (int kk = 0; kk < 2; ++kk) {
            int row = w * 32 + m * 16 + c, ch = kk * 4 + g;
            qf[m][kk] = *(const bf16x8*)(Ps + row * 128 + ((ch ^ (row & 7)) << 4));
        }

    float rinv[2][4];
    unsigned rowoff[2][4];
    #pragma unroll
    for (int m = 0; m < 2; ++m)
        #pragma unroll
        for (int r = 0; r < 4; ++r) {
            int ql = w * 32 + m * 16 + g * 4 + r;
            rinv[m][r] = rinvWS[virt * QT + ql];
            rowoff[m][r] = (unsigned)(qrowbase + ql) * (unsigned)S_LEN;
        }

    f32x4 pacc[2][4];
    #pragma unroll
    for (int m = 0; m < 2; ++m)
        #pragma unroll
        for (int d = 0; d < 4; ++d) pacc[m][d] = (f32x4){0.f,0.f,0.f,0.f};

    // prefetch K,V tile 0
    float kpre[32], vpre[32];
    #pragma unroll
    for (int i = 0; i < 4; ++i) {
        int flat = i * NTHR + t, row = flat >> 3, ch = flat & 7;
        const float* src = Kg + (kbase0 + row) * D_DIM + ch * 8;
        float4 a = *(const float4*)src, b = *(const float4*)(src + 4);
        kpre[i*8+0]=a.x; kpre[i*8+1]=a.y; kpre[i*8+2]=a.z; kpre[i*8+3]=a.w;
        kpre[i*8+4]=b.x; kpre[i*8+5]=b.y; kpre[i*8+6]=b.z; kpre[i*8+7]=b.w;
    }
    #pragma unroll
    for (int i = 0; i < 2; ++i) {
        int task = i * NTHR + t, dg = task & 7, k0 = (task >> 3) * 2;
        const float* src = Vg + (kbase0 + k0) * D_DIM + dg * 8;
        float4 a = *(const float4*)src,        b = *(const float4*)(src + 4);
        float4 e = *(const float4*)(src + 64), f = *(const float4*)(src + 68);
        vpre[i*16+ 0]=a.x; vpre[i*16+ 1]=a.y; vpre[i*16+ 2]=a.z; vpre[i*16+ 3]=a.w;
        vpre[i*16+ 4]=b.x; vpre[i*16+ 5]=b.y; vpre[i*16+ 6]=b.z; vpre[i*16+ 7]=b.w;
        vpre[i*16+ 8]=e.x; vpre[i*16+ 9]=e.y; vpre[i*16+10]=e.z; vpre[i*16+11]=e.w;
        vpre[i*16+12]=f.x; vpre[i*16+13]=f.y; vpre[i*16+14]=f.z; vpre[i*16+15]=f.w;
    }

    for (int kt = 0; kt < NKT; ++kt) {
        __syncthreads();                 // A: prev QK(Ks) + PV(Ps,Vt) reads done

        // stage K (bf16x8 swizzled) and V (transposed, k-pair packed b32)
        #pragma unroll
        for (int i = 0; i < 4; ++i) {
            int flat = i * NTHR + t, row = flat >> 3, ch = flat & 7;
            bf16x8 hv;
            #pragma unroll
            for (int j = 0; j < 8; ++j) hv[j] = (short)f2bf(kpre[i*8+j]);
            *(bf16x8*)(Ks + row * 128 + ((ch ^ (row & 7)) << 4)) = hv;
        }
        #pragma unroll
        for (int i = 0; i < 2; ++i) {
            int task = i * NTHR + t, dg = task & 7, k0 = (task >> 3) * 2;
            #pragma unroll
            for (int j = 0; j < 8; ++j) {
                unsigned pk = (unsigned)f2bf(vpre[i*16+j]) |
                              ((unsigned)f2bf(vpre[i*16+8+j]) << 16);
                int d = dg * 8 + j;
                *(unsigned*)(Vt + d * 256 + (((k0 >> 3) ^ (d & 15)) << 4) + (k0 & 7) * 2) = pk;
            }
        }
        // issue next-tile global loads (land under the compute below)
        if (kt + 1 < NKT) {
            #pragma unroll
            for (int i = 0; i < 4; ++i) {
                int flat = i * NTHR + t, row = flat >> 3, ch = flat & 7;
                const float* src = Kg + (kbase0 + (kt+1)*KT + row) * D_DIM + ch * 8;
                float4 a = *(const float4*)src, b = *(const float4*)(src + 4);
                kpre[i*8+0]=a.x; kpre[i*8+1]=a.y; kpre[i*8+2]=a.z; kpre[i*8+3]=a.w;
                kpre[i*8+4]=b.x; kpre[i*8+5]=b.y; kpre[i*8+6]=b.z; kpre[i*8+7]=b.w;
            }
            #pragma unroll
            for (int i = 0; i < 2; ++i) {
                int task = i * NTHR + t, dg = task & 7, k0 = (task >> 3) * 2;
                const float* src = Vg + (kbase0 + (kt+1)*KT + k0) * D_DIM + dg * 8;
                float4 a = *(const float4*)src,        b = *(const float4*)(src + 4);
                float4 e = *(const float4*)(src + 64), f = *(const float4*)(src + 68);
                vpre[i*16+ 0]=a.x; vpre[i*16+ 1]=a.y; vpre[i*16+ 2]=a.z; vpre[i*16+ 3]=a.w;
                vpre[i*16+ 4]=b.x; vpre[i*16+ 5]=b.y; vpre[i*16+ 6]=b.z; vpre[i*16+ 7]=b.w;
                vpre[i*16+ 8]=e.x; vpre[i*16+ 9]=e.y; vpre[i*16+10]=e.z; vpre[i*16+11]=e.w;
                vpre[i*16+12]=f.x; vpre[i*16+13]=f.y; vpre[i*16+14]=f.z; vpre[i*16+15]=f.w;
            }
        }
        __syncthreads();                 // B: Ks, Vt ready

        unsigned long long bits =
            useWS ? bitsWS[((unsigned)virt * NKT + kt) * NTHR + t] : 0ull;
        const unsigned kcb = (unsigned)(kt * KT + c);
        #pragma unroll
        for (int n = 0; n < 8; ++n) {
            int rowk = n * 16 + c;
            bf16x8 b0 = *(const bf16x8*)(Ks + rowk * 128 + (((0 + g) ^ (rowk & 7)) << 4));
            bf16x8 b1 = *(const bf16x8*)(Ks + rowk * 128 + (((4 + g) ^ (rowk & 7)) << 4));
            f32x4 a0 = {0.f,0.f,0.f,0.f}, a1 = {0.f,0.f,0.f,0.f};
            a0 = __builtin_amdgcn_mfma_f32_16x16x32_bf16(qf[0][0], b0, a0, 0, 0, 0);
            a0 = __builtin_amdgcn_mfma_f32_16x16x32_bf16(qf[0][1], b1, a0, 0, 0, 0);
            a1 = __builtin_amdgcn_mfma_f32_16x16x32_bf16(qf[1][0], b0, a1, 0, 0, 0);
            a1 = __builtin_amdgcn_mfma_f32_16x16x32_bf16(qf[1][1], b1, a1, 0, 0, 0);
            #pragma unroll
            for (int m = 0; m < 2; ++m) {
                f32x4 am = m ? a1 : a0;
                #pragma unroll
                for (int r = 0; r < 4; ++r) {
                    unsigned idx = rowoff[m][r] + kcb + n * 16;
                    int mk;
                    if (useWS) {
                        mk = (int)((bits >> ((m << 5) | (n << 2) | r)) & 1ull);
                    } else if (mask32) {
                        mk = __builtin_nontemporal_load(((const int*)maskB) + idx);
                    } else {
                        mk = (int)__builtin_nontemporal_load(maskB + idx);
                    }
                    float aval = mk ? 0.f : __expf(am[r] * 0.125f) * rinv[m][r];
                    __builtin_nontemporal_store(aval, attnOut + idx);
                    int q = w * 32 + m * 16 + g * 4 + r;
                    int k = n * 16 + c;
                    *(unsigned short*)(Ps + q * 256 + ((((k >> 3) ^ (q & 15)) << 4)) + (k & 7) * 2)
                        = f2bf(aval);
                }
            }
        }
        __syncthreads();                 // C: P tile ready

        // PV: prob += P(128xKT) * V(KTx64), bf16 MFMA
        #pragma unroll
        for (int kk = 0; kk < 4; ++kk) {
            int q0 = w * 32 + c, q1 = q0 + 16;
            int chv = kk * 4 + g;
            bf16x8 pa0 = *(const bf16x8*)(Ps + q0 * 256 + ((chv ^ (q0 & 15)) << 4));
            bf16x8 pa1 = *(const bf16x8*)(Ps + q1 * 256 + ((chv ^ (q1 & 15)) << 4));
            #pragma unroll
            for (int df = 0; df < 4; ++df) {
                int d = df * 16 + c;
                bf16x8 vb = *(const bf16x8*)(Vt + d * 256 + ((chv ^ (d & 15)) << 4));
                pacc[0][df] = __builtin_amdgcn_mfma_f32_16x16x32_bf16(pa0, vb, pacc[0][df], 0, 0, 0);
                pacc[1][df] = __builtin_amdgcn_mfma_f32_16x16x32_bf16(pa1, vb, pacc[1][df], 0, 0, 0);
            }
        }
    }

    // epilogue: prob
    #pragma unroll
    for (int m = 0; m < 2; ++m)
        #pragma unroll
        for (int df = 0; df < 4; ++df)
            #pragma unroll
            for (int r = 0; r < 4; ++r) {
                int ql = w * 32 + m * 16 + g * 4 + r;
                probOut[(long long)(qrowbase + ql) * D_DIM + df * 16 + c] = pacc[m][df][r];
            }
}

// -------------------------------------------------------------------------
extern "C" void kernel_launch(void* const* d_in, const int* in_sizes, int n_in,
                              void* d_out, int out_size, void* d_ws, size_t ws_size,
                              hipStream_t stream) {
    const float* Q = (const float*)d_in[0];
    const float* K = (const float*)d_in[1];
    const float* V = (const float*)d_in[2];
    const unsigned char* mask = (const unsigned char*)d_in[3];

    float* prob = (float*)d_out;
    float* attn = (float*)d_out + PROB_ELEMS;

    int* flag = (int*)d_ws;
    float* rinvWS = (float*)((char*)d_ws + 256);                       // 512*128 f32
    unsigned long long* bitsWS = (unsigned long long*)((char*)d_ws + 262400);
    const size_t bits_bytes = (size_t)NBLK * NKT * NTHR * 8ull;        // 16.78 MB
    const int useWS = (ws_size >= (size_t)262400 + bits_bytes) ? 1 : 0;

    mask_probe_kernel<<<1, 64, 0, stream>>>((const unsigned int*)mask, flag);
    attn_sweep1<<<NBLK, NTHR, 0, stream>>>(Q, K, mask, flag, rinvWS, bitsWS, useWS);
    attn_sweep2<<<NBLK, NTHR, 0, stream>>>(Q, K, V, mask, flag, rinvWS, bitsWS, useWS,
                                           attn, prob);
}